// Round 9
// baseline (51739.093 us; speedup 1.0000x reference)
//
#include <hip/hip_runtime.h>
#include <cstdint>
#include <cstddef>

// ---------------------------------------------------------------------------
// 5-layer stacked LSTM (B=4096, T=256, H=50, D_in=1) + FC head, fp32.
//
// R9: R8 confirmed LDS-pipe instruction-throughput bound: broadcast
// ds_read_b128 costs ~12 cyc (same as lane-distinct); 1664 LDS instr/CU/step
// = 20.1k cyc/step. Fix: (a) 2 gates/thread (halves LDS instrs/fma),
// (b) x-side GEMM via v_readlane broadcast (VALU pipe, per-SIMD) instead of
// LDS; only the h-side uses LDS b128 broadcasts.
// 1024 blocks x 128 threads (2 waves), 4 rows/block. Thread tid<100 owns
// gates (tid, tid+100): 52 float4 = 208 weight VGPRs (launch_bounds(128,1):
// no VGPR cap promise -> no spill; ~245 total -> 2 waves/SIMD).
// ys layout [t][row][k] so lane k loads x[r][k] coalesced; readlane(k)
// broadcasts it via SGPR into both gates' fmas.
// LDS/CU/step: 8 waves x 52 b128 = 416 instr (~5.0k cyc) vs R8's 1664.
// ---------------------------------------------------------------------------

#define HSZ   50
#define G4    200
#define TS    256
#define RPB   4              // batch rows per block
#define NB    (4096 / RPB)   // 1024 blocks
#define NT    128            // threads (2 waves)
#define HP    56             // padded h row stride (13 float4 + pad)

__device__ __forceinline__ float sigf(float x) {
  return __builtin_amdgcn_rcpf(1.0f + __expf(-x));
}
__device__ __forceinline__ float tanh_f(float x) {
  return fmaf(2.0f, __builtin_amdgcn_rcpf(1.0f + __expf(-2.0f * x)), -1.0f);
}
__device__ __forceinline__ int div50(int v) { return (int)(((unsigned)v * 5243u) >> 18); }
__device__ __forceinline__ float rdlane(float v, int k) {
  return __int_as_float(__builtin_amdgcn_readlane(__float_as_int(v), k));
}

// load a 50-float weight row (8B-aligned) into 13 float4 regs, tail zeroed
__device__ __forceinline__ void load_row50(const float* __restrict__ p, float4 w[13]) {
  #pragma unroll
  for (int kk = 0; kk < 12; ++kk) {
    float2 e0 = *(const float2*)(p + kk * 4);
    float2 e1 = *(const float2*)(p + kk * 4 + 2);
    w[kk] = make_float4(e0.x, e0.y, e1.x, e1.y);
  }
  float2 tl = *(const float2*)(p + 48);
  w[12] = make_float4(tl.x, tl.y, 0.0f, 0.0f);
}

__global__ void __launch_bounds__(NT, 1)
lstm5_kernel(const float* __restrict__ x,
             const float* __restrict__ w_ih0, const float* __restrict__ w_hh0,
             const float* __restrict__ b0,
             const float* __restrict__ w_ih,  const float* __restrict__ w_hh,
             const float* __restrict__ b,
             const float* __restrict__ fc_w,  const float* __restrict__ fc_b,
             float* __restrict__ out, float* __restrict__ ys)
{
  __shared__ __align__(16) float s_h[RPB * HP];   // 896 B: h rows, padded
  __shared__ __align__(16) float s_g[RPB * G4];   // 3200 B: gates [row][gate]

  const int tid  = threadIdx.x;
  const int blk  = blockIdx.x;
  const int row0 = blk * RPB;
  const int lane = tid & 63;
  const int lcl  = (lane < HSZ) ? lane : (HSZ - 1);  // clamped k for vX loads
  const bool gt  = (tid < 100);
  const int  g0  = gt ? tid : 99;
  const int  g1  = g0 + 100;
  // pointwise items: i0 = tid (all threads), i1 = tid + 128 (tid < 72)
  const int  pr0  = div50(tid);
  const int  phu0 = tid - 50 * pr0;
  const bool has1 = (tid < G4 - NT);
  const int  i1   = tid + NT;
  const int  pr1  = div50(i1);
  const int  phu1 = i1 - 50 * pr1;
  float* __restrict__ ysb = ys + (size_t)blk * (TS * G4);

  float4 wihA[13], wihB[13], whhA[13], whhB[13];
  float  biasA = 0.0f, biasB = 0.0f, wxA = 0.0f, wxB = 0.0f;

  for (int layer = 0; layer < 5; ++layer) {
    // -------------- load this thread's 2 gates' weights into registers -----
    if (gt) {
      if (layer == 0) {
        wxA = w_ih0[g0];  wxB = w_ih0[g1];
        load_row50(w_hh0 + (size_t)g0 * HSZ, whhA);
        load_row50(w_hh0 + (size_t)g1 * HSZ, whhB);
        biasA = b0[g0];  biasB = b0[g1];
      } else {
        const float* Wih = w_ih + (size_t)(layer - 1) * G4 * HSZ;
        const float* Whh = w_hh + (size_t)(layer - 1) * G4 * HSZ;
        load_row50(Wih + (size_t)g0 * HSZ, wihA);
        load_row50(Wih + (size_t)g1 * HSZ, wihB);
        load_row50(Whh + (size_t)g0 * HSZ, whhA);
        load_row50(Whh + (size_t)g1 * HSZ, whhB);
        biasA = b[(size_t)(layer - 1) * G4 + g0];
        biasB = b[(size_t)(layer - 1) * G4 + g1];
      }
    }
    // zero h (incl. pads); reset cell states
    for (int i = tid; i < RPB * HP; i += NT) s_h[i] = 0.0f;
    float cst0 = 0.0f, cst1 = 0.0f;
    __syncthreads();

    // ------------------------------ time loop ------------------------------
    for (int t = 0; t < TS; ++t) {
      // x inputs for step t (issued first; latency hides under h-side GEMM).
      // layer 0: uniform scalar per row. layer>=1: lane k holds x[r][k]
      // (coalesced; ysb[t] not yet overwritten -> race-free, reads drain at
      // the barrier before pointwise writes).
      float xv[RPB];
      if (layer == 0) {
        #pragma unroll
        for (int r = 0; r < RPB; ++r) xv[r] = x[(size_t)(row0 + r) * TS + t];
      } else {
        #pragma unroll
        for (int r = 0; r < RPB; ++r) xv[r] = ysb[t * G4 + r * HSZ + lcl];
      }

      float a0[RPB], a1[RPB];
      #pragma unroll
      for (int r = 0; r < RPB; ++r) { a0[r] = biasA; a1[r] = biasB; }

      // ---- h-side: LDS b128 broadcasts (kk-outer for 8-chain ILP) ----
      #pragma unroll
      for (int kk = 0; kk < 13; ++kk) {
        #pragma unroll
        for (int r = 0; r < RPB; ++r) {
          float4 hv = *(const float4*)(s_h + r * HP + kk * 4);
          a0[r] = fmaf(whhA[kk].x, hv.x, a0[r]);
          a0[r] = fmaf(whhA[kk].y, hv.y, a0[r]);
          a0[r] = fmaf(whhA[kk].z, hv.z, a0[r]);
          a0[r] = fmaf(whhA[kk].w, hv.w, a0[r]);
          a1[r] = fmaf(whhB[kk].x, hv.x, a1[r]);
          a1[r] = fmaf(whhB[kk].y, hv.y, a1[r]);
          a1[r] = fmaf(whhB[kk].z, hv.z, a1[r]);
          a1[r] = fmaf(whhB[kk].w, hv.w, a1[r]);
        }
      }

      // ---- x-side: VALU readlane broadcasts (no LDS pipe) ----
      if (layer == 0) {
        #pragma unroll
        for (int r = 0; r < RPB; ++r) {   // xv[r] is wave-uniform here
          a0[r] = fmaf(wxA, xv[r], a0[r]);
          a1[r] = fmaf(wxB, xv[r], a1[r]);
        }
      } else {
        #pragma unroll
        for (int k = 0; k < HSZ; ++k) {
          const int kk = k >> 2, kc = k & 3;
          #pragma unroll
          for (int r = 0; r < RPB; ++r) {
            float s = rdlane(xv[r], k);
            float wA = (kc == 0) ? wihA[kk].x : (kc == 1) ? wihA[kk].y
                     : (kc == 2) ? wihA[kk].z : wihA[kk].w;
            float wB = (kc == 0) ? wihB[kk].x : (kc == 1) ? wihB[kk].y
                     : (kc == 2) ? wihB[kk].z : wihB[kk].w;
            a0[r] = fmaf(wA, s, a0[r]);
            a1[r] = fmaf(wB, s, a1[r]);
          }
        }
      }

      if (gt) {
        #pragma unroll
        for (int r = 0; r < RPB; ++r) {
          s_g[r * G4 + g0] = a0[r];   // lane-consecutive b32 stores
          s_g[r * G4 + g1] = a1[r];
        }
      }
      __syncthreads();   // gates visible; xv reads of ysb[t] drained

      // ---- pointwise: items i0 = tid, i1 = tid+128 ----
      {
        float gi = s_g[pr0 * G4 + phu0];
        float gf = s_g[pr0 * G4 + phu0 + 50];
        float gg = s_g[pr0 * G4 + phu0 + 100];
        float go = s_g[pr0 * G4 + phu0 + 150];
        float c  = fmaf(sigf(gf), cst0, sigf(gi) * tanh_f(gg));
        cst0 = c;
        float h  = sigf(go) * tanh_f(c);
        s_h[pr0 * HP + phu0] = h;
        if (layer < 4) ysb[t * G4 + tid] = h;          // [t][row][k] coalesced
      }
      if (has1) {
        float gi = s_g[pr1 * G4 + phu1];
        float gf = s_g[pr1 * G4 + phu1 + 50];
        float gg = s_g[pr1 * G4 + phu1 + 100];
        float go = s_g[pr1 * G4 + phu1 + 150];
        float c  = fmaf(sigf(gf), cst1, sigf(gi) * tanh_f(gg));
        cst1 = c;
        float h  = sigf(go) * tanh_f(c);
        s_h[pr1 * HP + phu1] = h;
        if (layer < 4) ysb[t * G4 + i1] = h;
      }
      __syncthreads();   // h_t visible for next step's h-side reads
    }
  }

  // ------------------------------- FC head ---------------------------------
  if (tid < RPB) {
    float a2 = fc_b[0];
    const float* hr = s_h + tid * HP;
    #pragma unroll
    for (int k = 0; k < HSZ; ++k) a2 = fmaf(hr[k], fc_w[k], a2);
    out[row0 + tid] = a2;
  }
}

extern "C" void kernel_launch(void* const* d_in, const int* in_sizes, int n_in,
                              void* d_out, int out_size, void* d_ws, size_t ws_size,
                              hipStream_t stream) {
  (void)in_sizes; (void)n_in; (void)out_size; (void)ws_size;
  const float* x     = (const float*)d_in[0];
  const float* w_ih0 = (const float*)d_in[1];
  const float* w_hh0 = (const float*)d_in[2];
  const float* b0    = (const float*)d_in[3];
  const float* w_ih  = (const float*)d_in[4];
  const float* w_hh  = (const float*)d_in[5];
  const float* b     = (const float*)d_in[6];
  const float* fc_w  = (const float*)d_in[7];
  const float* fc_b  = (const float*)d_in[8];
  float* out = (float*)d_out;
  float* ys  = (float*)d_ws;   // 1024 * 256 * 200 * 4 B = 209,715,200 B

  hipLaunchKernelGGL(lstm5_kernel, dim3(NB), dim3(NT), 0, stream,
                     x, w_ih0, w_hh0, b0, w_ih, w_hh, b, fc_w, fc_b, out, ys);
}

// Round 10
// 10273.733 us; speedup vs baseline: 5.0361x; 5.0361x over previous
//
#include <hip/hip_runtime.h>
#include <cstdint>
#include <cstddef>

// ---------------------------------------------------------------------------
// 5-layer stacked LSTM (B=4096, T=256, H=50, D_in=1) + FC head, fp32.
//
// R10: all-VALU GEMM via v_readlane broadcasts. R8 proved the LDS pipe is the
// wall (~12cyc/instr even for broadcast b128; 1664 instr/CU/step = 20k cyc).
// R9 proved 2 gates/thread spills (VGPR=256 cap, 27GB scratch traffic).
// Here: 1 gate/thread (100 weight VGPRs), GEMM reads activations from lane-
// distributed VGPRs via readlane->SGPR->fma. LDS only for tiny h/gate bounce.
// 512 blocks x 256 threads (4 waves), 8 rows/block -> exactly 2 blocks/CU
// resident (~150 VGPR), no second dispatch wave.
// Per wave per step: 800 readlane + 800 fma (+16 LDS b32) vs R8's 416 LDS
// b128. Per SIMD: 2 waves x 1600 x 2cyc = 6400 cyc/step -> ~3.9 ms predicted.
// ys layout [t][r*50+k] so lane k loads coalesced; 209,715,200 B of d_ws.
// ---------------------------------------------------------------------------

#define HSZ   50
#define G4    200
#define TS    256
#define RPB   8              // batch rows per block
#define NB    (4096 / RPB)   // 512 blocks
#define NT    256            // threads (4 waves)
#define HP    64             // s_h row stride
#define YROW  (RPB * HSZ)    // 400 floats per t in ysb

__device__ __forceinline__ float sigf(float x) {
  return __builtin_amdgcn_rcpf(1.0f + __expf(-x));
}
__device__ __forceinline__ float tanh_f(float x) {
  return fmaf(2.0f, __builtin_amdgcn_rcpf(1.0f + __expf(-2.0f * x)), -1.0f);
}
__device__ __forceinline__ float rdlane(float v, int k) {
  return __int_as_float(__builtin_amdgcn_readlane(__float_as_int(v), k));
}

// load a 50-float weight row (8B-aligned: 200B row stride) into scalar regs
__device__ __forceinline__ void load50(const float* __restrict__ p, float w[HSZ]) {
  #pragma unroll
  for (int q = 0; q < 25; ++q) {
    float2 e = *(const float2*)(p + q * 2);
    w[q * 2] = e.x;  w[q * 2 + 1] = e.y;
  }
}

__global__ void __launch_bounds__(NT, 2)
lstm5_kernel(const float* __restrict__ x,
             const float* __restrict__ w_ih0, const float* __restrict__ w_hh0,
             const float* __restrict__ b0,
             const float* __restrict__ w_ih,  const float* __restrict__ w_hh,
             const float* __restrict__ b,
             const float* __restrict__ fc_w,  const float* __restrict__ fc_b,
             float* __restrict__ out, float* __restrict__ ys)
{
  __shared__ __align__(16) float s_h[RPB * HP];   // 2048 B, lane k reads r*64+k
  __shared__ __align__(16) float s_g[RPB * G4];   // 6400 B, [row][gate]

  const int tid  = threadIdx.x;
  const int blk  = blockIdx.x;
  const int row0 = blk * RPB;
  const int lane = tid & 63;
  const int lcl  = (lane < HSZ) ? lane : (HSZ - 1);
  const bool gt  = (tid < G4);
  const int  g   = gt ? tid : (G4 - 1);
  // pointwise items: (pr0, phu) and (pr0+4, phu), active iff phu < 50
  const int  phu = tid & 63;
  const int  pr0 = tid >> 6;           // 0..3
  const bool pw  = (phu < HSZ);
  float* __restrict__ ysb = ys + (size_t)blk * (TS * YROW);

  float wI[HSZ], wH[HSZ];
  float bias = 0.0f, wx0 = 0.0f;

  for (int layer = 0; layer < 5; ++layer) {
    // ------------- load this thread's gate weights into registers ----------
    if (layer == 0) {
      wx0  = w_ih0[g];
      load50(w_hh0 + (size_t)g * HSZ, wH);
      bias = b0[g];
    } else {
      load50(w_ih + (size_t)(layer - 1) * G4 * HSZ + (size_t)g * HSZ, wI);
      load50(w_hh + (size_t)(layer - 1) * G4 * HSZ + (size_t)g * HSZ, wH);
      bias = b[(size_t)(layer - 1) * G4 + g];
    }
    // zero h; reset cell state; preload x for t=0
    s_h[tid] = 0.0f;  s_h[tid + NT] = 0.0f;
    float cst0 = 0.0f, cst1 = 0.0f;
    float vx[RPB];
    if (layer == 0) {
      #pragma unroll
      for (int r = 0; r < RPB; ++r) vx[r] = x[(size_t)(row0 + r) * TS];
    } else {
      #pragma unroll
      for (int r = 0; r < RPB; ++r) vx[r] = ysb[r * HSZ + lcl];
    }
    __syncthreads();

    // ------------------------------ time loop ------------------------------
    for (int t = 0; t < TS; ++t) {
      // current h, lane-distributed (8 lane-distinct b32, conflict-free)
      float vh[RPB];
      #pragma unroll
      for (int r = 0; r < RPB; ++r) vh[r] = s_h[r * HP + lcl];

      // prefetch next step's x (latency hides under the 1600-instr GEMM)
      const int nt2 = (t + 1 < TS) ? (t + 1) : t;
      float vxn[RPB];
      if (layer == 0) {
        #pragma unroll
        for (int r = 0; r < RPB; ++r) vxn[r] = x[(size_t)(row0 + r) * TS + nt2];
      } else {
        #pragma unroll
        for (int r = 0; r < RPB; ++r) vxn[r] = ysb[nt2 * YROW + r * HSZ + lcl];
      }

      // ---- gate GEMM: a[r] = bias + W_ih[g,:]*x_r + W_hh[g,:]*h_r ----
      float a[RPB];
      #pragma unroll
      for (int r = 0; r < RPB; ++r) a[r] = bias;

      if (layer == 0) {          // x is a wave-uniform scalar per row
        #pragma unroll
        for (int r = 0; r < RPB; ++r) a[r] = fmaf(wx0, vx[r], a[r]);
      } else {
        #pragma unroll
        for (int k = 0; k < HSZ; ++k) {
          #pragma unroll
          for (int r = 0; r < RPB; ++r)
            a[r] = fmaf(wI[k], rdlane(vx[r], k), a[r]);
        }
      }
      #pragma unroll
      for (int k = 0; k < HSZ; ++k) {
        #pragma unroll
        for (int r = 0; r < RPB; ++r)
          a[r] = fmaf(wH[k], rdlane(vh[r], k), a[r]);
      }

      if (gt) {
        #pragma unroll
        for (int r = 0; r < RPB; ++r) s_g[r * G4 + g] = a[r];  // consecutive
      }
      __syncthreads();   // gates visible

      // ---- pointwise: items (pr0, phu) and (pr0+4, phu) ----
      if (pw) {
        {
          const float* gp = s_g + pr0 * G4 + phu;
          float c = fmaf(sigf(gp[50]), cst0, sigf(gp[0]) * tanh_f(gp[100]));
          cst0 = c;
          float h = sigf(gp[150]) * tanh_f(c);
          s_h[pr0 * HP + phu] = h;
          if (layer < 4) ysb[t * YROW + pr0 * HSZ + phu] = h;
        }
        {
          const int pr1 = pr0 + 4;
          const float* gp = s_g + pr1 * G4 + phu;
          float c = fmaf(sigf(gp[50]), cst1, sigf(gp[0]) * tanh_f(gp[100]));
          cst1 = c;
          float h = sigf(gp[150]) * tanh_f(c);
          s_h[pr1 * HP + phu] = h;
          if (layer < 4) ysb[t * YROW + pr1 * HSZ + phu] = h;
        }
      }
      __syncthreads();   // h_t visible for next step's vh loads

      #pragma unroll
      for (int r = 0; r < RPB; ++r) vx[r] = vxn[r];
    }
  }

  // ------------------------------- FC head ---------------------------------
  if (tid < RPB) {
    float a2 = fc_b[0];
    const float* hr = s_h + tid * HP;
    #pragma unroll
    for (int k = 0; k < HSZ; ++k) a2 = fmaf(hr[k], fc_w[k], a2);
    out[row0 + tid] = a2;
  }
}

extern "C" void kernel_launch(void* const* d_in, const int* in_sizes, int n_in,
                              void* d_out, int out_size, void* d_ws, size_t ws_size,
                              hipStream_t stream) {
  (void)in_sizes; (void)n_in; (void)out_size; (void)ws_size;
  const float* x     = (const float*)d_in[0];
  const float* w_ih0 = (const float*)d_in[1];
  const float* w_hh0 = (const float*)d_in[2];
  const float* b0    = (const float*)d_in[3];
  const float* w_ih  = (const float*)d_in[4];
  const float* w_hh  = (const float*)d_in[5];
  const float* b     = (const float*)d_in[6];
  const float* fc_w  = (const float*)d_in[7];
  const float* fc_b  = (const float*)d_in[8];
  float* out = (float*)d_out;
  float* ys  = (float*)d_ws;   // 512 blocks * 256 t * 400 * 4 B = 209,715,200 B

  hipLaunchKernelGGL(lstm5_kernel, dim3(NB), dim3(NT), 0, stream,
                     x, w_ih0, w_hh0, b0, w_ih, w_hh, b, fc_w, fc_b, out, ys);
}